// Round 10
// baseline (173.862 us; speedup 1.0000x reference)
//
#include <hip/hip_runtime.h>
#include <hip/hip_bf16.h>

#define FH 240
#define FIT_IN 1600
#define NK 2048            // table knots per e
#define TLO -16.0f
#define TINVH 64.0f        // knots per unit S (h = 1/64)
#define KSPLIT0 8
#define CHUNK0 200

typedef _Float16 h8 __attribute__((ext_vector_type(8)));
typedef float f4v __attribute__((ext_vector_type(4)));

__device__ __forceinline__ float fast_tanh(float x) {
    float e2 = __builtin_amdgcn_exp2f(x * 2.8853900817779268f);
    return 1.0f - 2.0f * __builtin_amdgcn_rcpf(e2 + 1.0f);
}

#define FMA_ROW(r, s) \
    acc[r][0] += (s) * b0.x; acc[r][1] += (s) * b0.y; \
    acc[r][2] += (s) * b0.z; acc[r][3] += (s) * b0.w; \
    acc[r][4] += (s) * b1.x; acc[r][5] += (s) * b1.y; \
    acc[r][6] += (s) * b1.z; acc[r][7] += (s) * b1.w;

// ---------------------------------------------------------------------------
// k_prep: blocks 0..63 build the embedding table; blocks 64..511 convert
// fit weights to f16 transposed WT[tp][n][k]. (unchanged — proven)
// ---------------------------------------------------------------------------
#define TOFF_W0   0
#define TOFF_B0   28
#define TOFF_B1   56
#define TOFF_B2   108
#define TOFF_W1   208
#define TOFF_W2   1508
#define TOFF_H0T  6708
#define TOFF_H1T  10008
#define TSMEM     16608

__global__ __launch_bounds__(256) void k_prep(
    const float* __restrict__ eW0, const float* __restrict__ eB0,
    const float* __restrict__ eW1, const float* __restrict__ eB1,
    const float* __restrict__ eW2, const float* __restrict__ eB2,
    float* __restrict__ T,
    const float* __restrict__ fW0, const float* __restrict__ fW1,
    const float* __restrict__ fW2,
    _Float16* __restrict__ W0T, _Float16* __restrict__ W1T,
    _Float16* __restrict__ W2T)
{
    __shared__ float sm[TSMEM];
    const int t = threadIdx.x;

    if (blockIdx.x >= 64) {
        const int bid0 = blockIdx.x - 64;
        const int total = 768000 + 115200 + 115200;
        for (int idx = bid0 * 256 + t; idx < total; idx += 448 * 256) {
            if (idx < 768000) {
                const int tp = idx / 384000, r = idx - tp * 384000;
                const int n = r / 1600, k = r - n * 1600;
                W0T[idx] = (_Float16)fW0[tp * 384000 + k * 240 + n];
            } else if (idx < 883200) {
                const int j = idx - 768000;
                const int tp = j / 57600, r = j - tp * 57600;
                const int n = r / 240, k = r - n * 240;
                W1T[j] = (_Float16)fW1[tp * 57600 + k * 240 + n];
            } else {
                const int j = idx - 883200;
                const int tp = j / 57600, r = j - tp * 57600;
                const int n = r / 240, k = r - n * 240;
                W2T[j] = (_Float16)fW2[tp * 57600 + k * 240 + n];
            }
        }
        return;
    }

    const int w    = t >> 6;
    const int lane = t & 63;
    const int mi   = lane & 7;
    const int gi   = lane >> 3;
    const int mrow = w * 32 + mi * 4;

    const int e  = blockIdx.x >> 4;
    const int k0 = (blockIdx.x & 15) * 128;

    for (int idx = t; idx < 1250; idx += 256) {
        int k = idx / 50, g = idx - k * 50;
        sm[TOFF_W1 + k * 52 + g] = eW1[e * 1250 + idx];
    }
    for (int idx = t; idx < 5000; idx += 256) {
        int k = idx / 100, r = idx - k * 100;
        int half = r / 50, g = r - half * 50;
        sm[TOFF_W2 + k * 104 + half * 52 + g] = eW2[e * 5000 + idx];
    }
    if (t < 25)       { sm[TOFF_W0 + t] = eW0[e * 25 + t]; sm[TOFF_B0 + t] = eB0[e * 25 + t]; }
    else if (t < 75)  { sm[TOFF_B1 + (t - 25)] = eB1[e * 50 + (t - 25)]; }
    else if (t < 175) { sm[TOFF_B2 + (t - 75)] = eB2[e * 100 + (t - 75)]; }
    __syncthreads();

    if (t < 128) {
        const float S = TLO + (float)(k0 + t) * (1.0f / TINVH);
        #pragma unroll
        for (int k = 0; k < 25; ++k)
            sm[TOFF_H0T + k * 132 + t] = fast_tanh(S * sm[TOFF_W0 + k] + sm[TOFF_B0 + k]);
    }
    __syncthreads();

    {
        float acc[4][8];
        #pragma unroll
        for (int r = 0; r < 4; ++r)
            #pragma unroll
            for (int c = 0; c < 8; ++c) acc[r][c] = 0.f;

        #pragma unroll 5
        for (int k = 0; k < 25; ++k) {
            const float4 av = *(const float4*)&sm[TOFF_H0T + k * 132 + mrow];
            const float4 b0 = *(const float4*)&sm[TOFF_W1 + k * 52 + gi * 8];
            const float4 b1 = *(const float4*)&sm[TOFF_W1 + k * 52 + gi * 8 + 4];
            FMA_ROW(0, av.x) FMA_ROW(1, av.y) FMA_ROW(2, av.z) FMA_ROW(3, av.w)
        }
        #pragma unroll
        for (int c = 0; c < 8; ++c) {
            const int g = gi * 8 + c;
            if (g < 50) {
                const int gm = (g < 25) ? g : g - 25;
                const float4 h0r = *(const float4*)&sm[TOFF_H0T + gm * 132 + mrow];
                const float bias = sm[TOFF_B1 + g];
                float4 o;
                o.x = fast_tanh(acc[0][c] + bias) + h0r.x;
                o.y = fast_tanh(acc[1][c] + bias) + h0r.y;
                o.z = fast_tanh(acc[2][c] + bias) + h0r.z;
                o.w = fast_tanh(acc[3][c] + bias) + h0r.w;
                *(float4*)&sm[TOFF_H1T + g * 132 + mrow] = o;
            }
        }
    }
    __syncthreads();

    for (int half = 0; half < 2; ++half) {
        float acc[4][8];
        #pragma unroll
        for (int r = 0; r < 4; ++r)
            #pragma unroll
            for (int c = 0; c < 8; ++c) acc[r][c] = 0.f;

        #pragma unroll 5
        for (int k = 0; k < 50; ++k) {
            const float4 av = *(const float4*)&sm[TOFF_H1T + k * 132 + mrow];
            const float4 b0 = *(const float4*)&sm[TOFF_W2 + k * 104 + half * 52 + gi * 8];
            const float4 b1 = *(const float4*)&sm[TOFF_W2 + k * 104 + half * 52 + gi * 8 + 4];
            FMA_ROW(0, av.x) FMA_ROW(1, av.y) FMA_ROW(2, av.z) FMA_ROW(3, av.w)
        }
        #pragma unroll
        for (int c = 0; c < 8; ++c) {
            const int g = gi * 8 + c;
            if (g < 50) {
                const float4 h1r = *(const float4*)&sm[TOFF_H1T + g * 132 + mrow];
                const float bias = sm[TOFF_B2 + half * 50 + g];
                float* out = T + ((size_t)e * NK + k0 + mrow) * 100 + half * 50 + g;
                out[0]   = fast_tanh(acc[0][c] + bias) + h1r.x;
                out[100] = fast_tanh(acc[1][c] + bias) + h1r.y;
                out[200] = fast_tanh(acc[2][c] + bias) + h1r.z;
                out[300] = fast_tanh(acc[3][c] + bias) + h1r.w;
            }
        }
    }
}

// ---------------------------------------------------------------------------
// k_xyz: per atom: gather+lerp G from table, reduce xyz[c][g], emit DR (f16).
// (unchanged — proven)
// ---------------------------------------------------------------------------
__global__ __launch_bounds__(256) void k_xyz(
    const float* __restrict__ Ri, const float* __restrict__ T,
    _Float16* __restrict__ DRh)
{
    __shared__ float4 sR[256];
    __shared__ float  sF[256];
    __shared__ int    sI[256];
    __shared__ float  sXYZ[400];

    const int t   = threadIdx.x;
    const int blk = blockIdx.x;          // 0..2047
    const int b   = blk >> 9;
    const int i   = (blk >> 8) & 1;
    const int n   = blk & 255;

    for (int idx = t; idx < 400; idx += 256) sXYZ[idx] = 0.f;

    {
        const int jj = t >> 7, m = t & 127;
        const size_t row = ((size_t)(b * 512 + i * 256 + n)) * 256 + jj * 128 + m;
        const float4 r = *(const float4*)(Ri + row * 4);
        sR[t] = r;
        float u = (r.x - TLO) * TINVH;
        int ii = (int)u;
        ii = (ii < 0) ? 0 : ((ii > NK - 2) ? NK - 2 : ii);
        sI[t] = ii;
        sF[t] = u - (float)ii;
    }
    __syncthreads();

    const int jj = t >> 7;
    const int g  = t & 127;
    if (g < 100) {
        const float* Te = T + ((size_t)(i * 2 + jj)) * NK * 100 + g;
        float a0 = 0.f, a1 = 0.f, a2 = 0.f, a3 = 0.f;
        #pragma unroll 4
        for (int m = 0; m < 128; ++m) {
            const int s = jj * 128 + m;
            const float4 R = sR[s];
            const float  f = sF[s];
            const float* p = Te + (size_t)sI[s] * 100;
            const float v0 = p[0], v1 = p[100];
            const float G = v0 + f * (v1 - v0);
            a0 += R.x * G; a1 += R.y * G; a2 += R.z * G; a3 += R.w * G;
        }
        atomicAdd(&sXYZ[g],       a0);
        atomicAdd(&sXYZ[100 + g], a1);
        atomicAdd(&sXYZ[200 + g], a2);
        atomicAdd(&sXYZ[300 + g], a3);
    }
    __syncthreads();

    const float inv = 1.0f / 65536.0f;
    _Float16* dr = DRh + (((size_t)i * 4 + b) * 256 + n) * FIT_IN;
    for (int q = t; q < 400; q += 256) {
        const int gg = q >> 2, h0 = (q & 3) * 4;
        ushort4 pk;
        _Float16* ph = (_Float16*)&pk;
        #pragma unroll
        for (int r = 0; r < 4; ++r) {
            const int h = h0 + r;
            const float v = (sXYZ[gg] * sXYZ[h] + sXYZ[100 + gg] * sXYZ[100 + h]
                           + sXYZ[200 + gg] * sXYZ[200 + h] + sXYZ[300 + gg] * sXYZ[300 + h]) * inv;
            ph[r] = (_Float16)v;
        }
        *(ushort4*)(dr + gg * 16 + h0) = pk;
    }
}

// ---------------------------------------------------------------------------
// k_fit_mfma: layer-0 partial GEMM P[ks] = A[rows, kslice] @ W[kslice, 240].
// R4's EXACT proven kernel (est ~15.6us by ledger subtraction): 64-row
// M-tiles, 256 thr, 4 waves split N, grid (32, KSPLIT0=8), CHUNK=200,
// per-k-step cooperative LDS staging (2 barriers / 32-k-step).
// Layouts: A[m=lane&15][k=quad*8+j], B[k=quad*8+j][n=lane&15],
// D[row=quad*4+reg][col=lane&15].
// ---------------------------------------------------------------------------
template<int K, int CHUNK>
__global__ __launch_bounds__(256) void k_fit_mfma(
    const _Float16* __restrict__ A, const _Float16* __restrict__ WT,
    float* __restrict__ P)
{
    __shared__ _Float16 sA[64 * 40];     // [m][k] stride 40 (80 B, 16B-aligned)
    __shared__ _Float16 sBT[240 * 40];   // [n][k] stride 40

    const int t    = threadIdx.x;
    const int w    = t >> 6;
    const int lane = t & 63;
    const int ln   = lane & 15;
    const int quad = lane >> 4;

    const int mtile = blockIdx.x;        // 0..31
    const int ks    = blockIdx.y;
    const int row0  = mtile * 64;
    const int tp    = mtile >> 4;
    const int kbeg  = ks * CHUNK;
    const int kend  = (kbeg + CHUNK < K) ? (kbeg + CHUNK) : K;
    const int nf0   = w * 4;
    const int nfrags = (w < 3) ? 4 : 3;

    f4v acc[4][4];
    #pragma unroll
    for (int mf = 0; mf < 4; ++mf)
        #pragma unroll
        for (int nf = 0; nf < 4; ++nf) acc[mf][nf] = (f4v)0.f;

    const _Float16* Ab = A + (size_t)row0 * K;
    const _Float16* Wb = WT + (size_t)tp * 240 * K;

    for (int k0 = kbeg; k0 < kend; k0 += 32) {
        // stage A tile 64x32 (uint2 = 4 f16)
        #pragma unroll
        for (int q = t; q < 512; q += 256) {
            const int m = q >> 3, kq = (q & 7) * 4;
            const int k = k0 + kq;
            uint2 v = make_uint2(0u, 0u);
            if (k < kend) v = *(const uint2*)(Ab + (size_t)m * K + k);
            *(uint2*)&sA[m * 40 + kq] = v;
        }
        // stage W tile 240x32 from transposed WT (coalesced)
        for (int q = t; q < 1920; q += 256) {
            const int n = q >> 3, kq = (q & 7) * 4;
            const int k = k0 + kq;
            uint2 v = make_uint2(0u, 0u);
            if (k < kend) v = *(const uint2*)(Wb + (size_t)n * K + k);
            *(uint2*)&sBT[n * 40 + kq] = v;
        }
        __syncthreads();

        h8 afr[4];
        #pragma unroll
        for (int mf = 0; mf < 4; ++mf)
            afr[mf] = *(const h8*)&sA[(mf * 16 + ln) * 40 + quad * 8];
        #pragma unroll
        for (int nf = 0; nf < 4; ++nf) {
            if (nf < nfrags) {
                const h8 bfr = *(const h8*)&sBT[((nf0 + nf) * 16 + ln) * 40 + quad * 8];
                #pragma unroll
                for (int mf = 0; mf < 4; ++mf)
                    acc[mf][nf] = __builtin_amdgcn_mfma_f32_16x16x32_f16(
                        afr[mf], bfr, acc[mf][nf], 0, 0, 0);
            }
        }
        __syncthreads();
    }

    float* Pb = P + ((size_t)ks * 2048 + row0) * FH;
    #pragma unroll
    for (int nf = 0; nf < 4; ++nf) {
        if (nf < nfrags) {
            const int col = (nf0 + nf) * 16 + ln;
            #pragma unroll
            for (int mf = 0; mf < 4; ++mf)
                #pragma unroll
                for (int r = 0; r < 4; ++r) {
                    const int row = mf * 16 + quad * 4 + r;
                    Pb[(size_t)row * FH + col] = acc[mf][nf][r];
                }
        }
    }
}

// ---------------------------------------------------------------------------
// k_fit_tail: 128 blocks x 16 rows, 256 thr (4 waves).
//   phase A: h0 = tanh(sum_8 P + b0)    (R1-proven 8-slice reduce)
//   layers 1/2: four 64-row W quarters, T14 REG-BATCHED staging:
//     15 UNCONDITIONAL independent global_loads into registers (one waitcnt),
//     then 15 ds_writes. R8 measured the guarded per-iteration load/ds_write
//     chain at ~900cy/iter (13.8Kcy/quarter) — batching collapses that to
//     ~1 latency + issue. Last quarter clamps the source row to 47; LDS rows
//     48..63 hold duplicate data but are NEVER read (wave 3's frag f=15 is
//     skipped; waves 0..2 read rows <=47).
//   out = h2 . W3 + b3 (proven per-wave row dot).
// sStage pad cols 240..247 zero-filled once (R6 NaN fix); staging never
// writes cols >= 240.
// ---------------------------------------------------------------------------
__global__ __launch_bounds__(256) void k_fit_tail(
    const float* __restrict__ P,
    const _Float16* __restrict__ W1T, const _Float16* __restrict__ W2T,
    const float* __restrict__ fb0, const float* __restrict__ fb1,
    const float* __restrict__ fb2, const float* __restrict__ fW3,
    const float* __restrict__ fb3, float* __restrict__ out)
{
    __shared__ _Float16 sStage[64 * 248];     // 31.7 KB, W quarter [n_local][k]
    __shared__ _Float16 sAbuf[2][16 * 264];   // 2 x 8.4 KB, f16 A ping-pong
    __shared__ float    hRes[16 * 240];       // 15.4 KB, residual (single-owner)

    const int t    = threadIdx.x;
    const int w    = t >> 6;                  // 0..3
    const int lane = t & 63;
    const int ln   = lane & 15;
    const int quad = lane >> 4;
    const int r0   = blockIdx.x * 16;         // 0..2032
    const int tp   = r0 >> 10;

    // zero both sA buffers (covers k-pad cols 240..263)
    for (int q = t; q < 2 * 16 * 264; q += 256) ((_Float16*)sAbuf)[q] = (_Float16)0.f;
    // zero-fill sStage pad cols 240..247 for all 64 rows (NaN fix)
    if (t < 128) {
        const int n = t >> 1, kq = 240 + (t & 1) * 4;
        *(uint2*)&sStage[n * 248 + kq] = make_uint2(0u, 0u);
    }

    // ---- phase A: reduce P over 8 slices, +bias, tanh -> h0 ----
    #pragma unroll
    for (int j = 0; j < 15; ++j) {
        const int e = t + j * 256;            // 0..3839 == 16*240 exactly
        const int m = e / 240, col = e - m * 240;
        const size_t base = (size_t)(r0 + m) * FH + col;
        float s = 0.f;
        #pragma unroll
        for (int ks = 0; ks < KSPLIT0; ++ks)
            s += P[(size_t)ks * 2048 * FH + base];
        const float v = fast_tanh(s + fb0[tp * FH + col]);
        hRes[m * 240 + col] = v;
        sAbuf[0][m * 264 + col] = (_Float16)v;
    }

    // ---- layers 1,2: four 64-row quarters, batched reg staging ----
    for (int layer = 0; layer < 2; ++layer) {
        const _Float16* Wt = (layer == 0 ? W1T : W2T) + (size_t)tp * FH * FH;
        const float* Bias  = (layer == 0 ? fb1 : fb2) + tp * FH;
        const _Float16* inA = sAbuf[layer];
        _Float16* outA      = sAbuf[layer ^ 1];

        for (int p = 0; p < 4; ++p) {
            __syncthreads();                  // prev quarter's sStage reads done
            const int rmax = (p < 3) ? 63 : 47;   // clamp src row (last quarter)
            uint2 ld[15];
            #pragma unroll
            for (int j = 0; j < 15; ++j) {    // 15 independent loads, no guard
                const int q = t + j * 256;    // 0..3839; 60 uint2 per row
                const int n = q / 60, kq = (q - n * 60) * 4;
                const int nc = (n > rmax) ? rmax : n;
                ld[j] = *(const uint2*)(Wt + (size_t)(p * 64 + nc) * FH + kq);
            }
            #pragma unroll
            for (int j = 0; j < 15; ++j) {    // write-late (one waitcnt above)
                const int q = t + j * 256;
                const int n = q / 60, kq = (q - n * 60) * 4;
                *(uint2*)&sStage[n * 248 + kq] = ld[j];
            }
            __syncthreads();                  // stage visible

            const int f = p * 4 + w;          // frag this wave owns this quarter
            if (f < 15) {
                f4v acc = (f4v)0.f;
                #pragma unroll
                for (int s = 0; s < 8; ++s) { // K=240 padded to 256; pads are 0
                    const h8 afr = *(const h8*)&inA[ln * 264 + s * 32 + quad * 8];
                    const h8 bfr = *(const h8*)&sStage[(w * 16 + ln) * 248 + s * 32 + quad * 8];
                    acc = __builtin_amdgcn_mfma_f32_16x16x32_f16(afr, bfr, acc, 0, 0, 0);
                }
                const int col = f * 16 + ln;
                const float bias = Bias[col];
                #pragma unroll
                for (int r = 0; r < 4; ++r) {
                    const int m = quad * 4 + r;
                    const float v = fast_tanh(acc[r] + bias) + hRes[m * 240 + col];
                    hRes[m * 240 + col] = v;          // single-owner slot
                    outA[m * 264 + col] = (_Float16)v;
                }
            }
        }
    }
    __syncthreads();                          // h2 (hRes) complete

    // ---- out: per-wave row dot with W3 (h2 in hRes) ----
    const float* wv = fW3 + tp * FH;
    #pragma unroll
    for (int rr = 0; rr < 4; ++rr) {
        const int m = w * 4 + rr;
        float s = 0.f;
        for (int k = lane; k < FH; k += 64)
            s += hRes[m * 240 + k] * wv[k];
        #pragma unroll
        for (int off = 32; off > 0; off >>= 1) s += __shfl_down(s, off);
        if (lane == 0) {
            const int gr = r0 + m;
            const int b = (gr >> 8) & 3, n = gr & 255;
            out[b * 512 + tp * 256 + n] = s + fb3[tp];
        }
    }
}

// ---------------------------------------------------------------------------
extern "C" void kernel_launch(void* const* d_in, const int* in_sizes, int n_in,
                              void* d_out, int out_size, void* d_ws, size_t ws_size,
                              hipStream_t stream)
{
    const float* Ri  = (const float*)d_in[0];
    const float* eW0 = (const float*)d_in[1];
    const float* eB0 = (const float*)d_in[2];
    const float* eW1 = (const float*)d_in[3];
    const float* eB1 = (const float*)d_in[4];
    const float* eW2 = (const float*)d_in[5];
    const float* eB2 = (const float*)d_in[6];
    const float* fW0 = (const float*)d_in[7];
    const float* fb0 = (const float*)d_in[8];
    const float* fW1 = (const float*)d_in[9];
    const float* fb1 = (const float*)d_in[10];
    const float* fW2 = (const float*)d_in[11];
    const float* fb2 = (const float*)d_in[12];
    const float* fW3 = (const float*)d_in[13];
    const float* fb3 = (const float*)d_in[14];

    // workspace layout (bytes)
    char* p = (char*)d_ws;
    float* T   = (float*)p;                 p += (size_t)4 * NK * 100 * 4;           // 3.28 MB
    float* P   = (float*)p;                 p += (size_t)KSPLIT0 * 2048 * FH * 4;    // 15.7 MB
    _Float16* DRh = (_Float16*)p;           p += (size_t)2048 * FIT_IN * 2;          // 6.55 MB
    _Float16* W0T = (_Float16*)p;           p += (size_t)768000 * 2;                 // 1.54 MB
    _Float16* W1T = (_Float16*)p;           p += (size_t)115200 * 2;
    _Float16* W2T = (_Float16*)p;           p += (size_t)115200 * 2;

    k_prep<<<dim3(512), dim3(256), 0, stream>>>(eW0, eB0, eW1, eB1, eW2, eB2, T,
                                                fW0, fW1, fW2, W0T, W1T, W2T);
    k_xyz<<<dim3(2048), dim3(256), 0, stream>>>(Ri, T, DRh);

    // layer 0 partial GEMM: K=1600, CHUNK=200, KSPLIT=8, 64-row tiles (R4-proven)
    k_fit_mfma<FIT_IN, CHUNK0><<<dim3(32, KSPLIT0), dim3(256), 0, stream>>>(DRh, W0T, P);

    // fused tail: 8-slice reduce + layer1 + layer2 + output dot (batched staging)
    k_fit_tail<<<dim3(128), dim3(256), 0, stream>>>(P, W1T, W2T, fb0, fb1, fb2, fW3, fb3,
                                                    (float*)d_out);
}

// Round 11
// 173.822 us; speedup vs baseline: 1.0002x; 1.0002x over previous
//
#include <hip/hip_runtime.h>
#include <hip/hip_bf16.h>

#define FH 240
#define FIT_IN 1600
#define NK 2048            // table knots per e
#define TLO -16.0f
#define TINVH 64.0f        // knots per unit S (h = 1/64)
#define KSPLIT0 8
#define CHUNK0 200

typedef _Float16 h8 __attribute__((ext_vector_type(8)));
typedef float f4v __attribute__((ext_vector_type(4)));

__device__ __forceinline__ float fast_tanh(float x) {
    float e2 = __builtin_amdgcn_exp2f(x * 2.8853900817779268f);
    return 1.0f - 2.0f * __builtin_amdgcn_rcpf(e2 + 1.0f);
}

#define FMA_ROW(r, s) \
    acc[r][0] += (s) * b0.x; acc[r][1] += (s) * b0.y; \
    acc[r][2] += (s) * b0.z; acc[r][3] += (s) * b0.w; \
    acc[r][4] += (s) * b1.x; acc[r][5] += (s) * b1.y; \
    acc[r][6] += (s) * b1.z; acc[r][7] += (s) * b1.w;

// ---------------------------------------------------------------------------
// k_prep: blocks 0..63 build the embedding table (unchanged); blocks 64..511
// convert fit weights to f16 transposed WT[tp][n][k].
// CVT REWRITE (R11): enumerate the SOURCE, not the destination. Old code had
// consecutive lanes reading fW[k*240+n] at 960B stride (64 lines/wave-load,
// ~1M scattered 4B loads — same gather disease as R7's 73us tail). Now each
// thread handles 8 consecutive k of one n: 8 COALESCED row-reads (lanes sweep
// consecutive n), one 16B vector write (scattered but fire-and-forget).
// ---------------------------------------------------------------------------
#define TOFF_W0   0
#define TOFF_B0   28
#define TOFF_B1   56
#define TOFF_B2   108
#define TOFF_W1   208
#define TOFF_W2   1508
#define TOFF_H0T  6708
#define TOFF_H1T  10008
#define TSMEM     16608

__global__ __launch_bounds__(256) void k_prep(
    const float* __restrict__ eW0, const float* __restrict__ eB0,
    const float* __restrict__ eW1, const float* __restrict__ eB1,
    const float* __restrict__ eW2, const float* __restrict__ eB2,
    float* __restrict__ T,
    const float* __restrict__ fW0, const float* __restrict__ fW1,
    const float* __restrict__ fW2,
    _Float16* __restrict__ W0T, _Float16* __restrict__ W1T,
    _Float16* __restrict__ W2T)
{
    __shared__ float sm[TSMEM];
    const int t = threadIdx.x;

    if (blockIdx.x >= 64) {
        // ---- cvt: source-coalesced reads, 16B scatter writes ----
        // W0: 2tp x 200kp x 240n = 96000 items; W1/W2: 2tp x 30kp x 240n = 14400 each
        const int bid0 = blockIdx.x - 64;
        const int total = 96000 + 14400 + 14400;
        for (int idx = bid0 * 256 + t; idx < total; idx += 448 * 256) {
            const float* src;
            _Float16* dst;
            if (idx < 96000) {
                const int tp = idx / 48000, r = idx - tp * 48000;
                const int kp = r / 240, n = r - kp * 240;
                src = fW0 + (size_t)tp * 384000 + (size_t)(kp * 8) * 240 + n;
                dst = W0T + (size_t)tp * 384000 + (size_t)n * 1600 + kp * 8;
            } else if (idx < 110400) {
                const int j = idx - 96000;
                const int tp = j / 7200, r = j - tp * 7200;
                const int kp = r / 240, n = r - kp * 240;
                src = fW1 + (size_t)tp * 57600 + (size_t)(kp * 8) * 240 + n;
                dst = W1T + (size_t)tp * 57600 + (size_t)n * 240 + kp * 8;
            } else {
                const int j = idx - 110400;
                const int tp = j / 7200, r = j - tp * 7200;
                const int kp = r / 240, n = r - kp * 240;
                src = fW2 + (size_t)tp * 57600 + (size_t)(kp * 8) * 240 + n;
                dst = W2T + (size_t)tp * 57600 + (size_t)n * 240 + kp * 8;
            }
            h8 pk;
            #pragma unroll
            for (int jj = 0; jj < 8; ++jj) pk[jj] = (_Float16)src[(size_t)jj * 240];
            *(h8*)dst = pk;
        }
        return;
    }

    const int w    = t >> 6;
    const int lane = t & 63;
    const int mi   = lane & 7;
    const int gi   = lane >> 3;
    const int mrow = w * 32 + mi * 4;

    const int e  = blockIdx.x >> 4;
    const int k0 = (blockIdx.x & 15) * 128;

    for (int idx = t; idx < 1250; idx += 256) {
        int k = idx / 50, g = idx - k * 50;
        sm[TOFF_W1 + k * 52 + g] = eW1[e * 1250 + idx];
    }
    for (int idx = t; idx < 5000; idx += 256) {
        int k = idx / 100, r = idx - k * 100;
        int half = r / 50, g = r - half * 50;
        sm[TOFF_W2 + k * 104 + half * 52 + g] = eW2[e * 5000 + idx];
    }
    if (t < 25)       { sm[TOFF_W0 + t] = eW0[e * 25 + t]; sm[TOFF_B0 + t] = eB0[e * 25 + t]; }
    else if (t < 75)  { sm[TOFF_B1 + (t - 25)] = eB1[e * 50 + (t - 25)]; }
    else if (t < 175) { sm[TOFF_B2 + (t - 75)] = eB2[e * 100 + (t - 75)]; }
    __syncthreads();

    if (t < 128) {
        const float S = TLO + (float)(k0 + t) * (1.0f / TINVH);
        #pragma unroll
        for (int k = 0; k < 25; ++k)
            sm[TOFF_H0T + k * 132 + t] = fast_tanh(S * sm[TOFF_W0 + k] + sm[TOFF_B0 + k]);
    }
    __syncthreads();

    {
        float acc[4][8];
        #pragma unroll
        for (int r = 0; r < 4; ++r)
            #pragma unroll
            for (int c = 0; c < 8; ++c) acc[r][c] = 0.f;

        #pragma unroll 5
        for (int k = 0; k < 25; ++k) {
            const float4 av = *(const float4*)&sm[TOFF_H0T + k * 132 + mrow];
            const float4 b0 = *(const float4*)&sm[TOFF_W1 + k * 52 + gi * 8];
            const float4 b1 = *(const float4*)&sm[TOFF_W1 + k * 52 + gi * 8 + 4];
            FMA_ROW(0, av.x) FMA_ROW(1, av.y) FMA_ROW(2, av.z) FMA_ROW(3, av.w)
        }
        #pragma unroll
        for (int c = 0; c < 8; ++c) {
            const int g = gi * 8 + c;
            if (g < 50) {
                const int gm = (g < 25) ? g : g - 25;
                const float4 h0r = *(const float4*)&sm[TOFF_H0T + gm * 132 + mrow];
                const float bias = sm[TOFF_B1 + g];
                float4 o;
                o.x = fast_tanh(acc[0][c] + bias) + h0r.x;
                o.y = fast_tanh(acc[1][c] + bias) + h0r.y;
                o.z = fast_tanh(acc[2][c] + bias) + h0r.z;
                o.w = fast_tanh(acc[3][c] + bias) + h0r.w;
                *(float4*)&sm[TOFF_H1T + g * 132 + mrow] = o;
            }
        }
    }
    __syncthreads();

    for (int half = 0; half < 2; ++half) {
        float acc[4][8];
        #pragma unroll
        for (int r = 0; r < 4; ++r)
            #pragma unroll
            for (int c = 0; c < 8; ++c) acc[r][c] = 0.f;

        #pragma unroll 5
        for (int k = 0; k < 50; ++k) {
            const float4 av = *(const float4*)&sm[TOFF_H1T + k * 132 + mrow];
            const float4 b0 = *(const float4*)&sm[TOFF_W2 + k * 104 + half * 52 + gi * 8];
            const float4 b1 = *(const float4*)&sm[TOFF_W2 + k * 104 + half * 52 + gi * 8 + 4];
            FMA_ROW(0, av.x) FMA_ROW(1, av.y) FMA_ROW(2, av.z) FMA_ROW(3, av.w)
        }
        #pragma unroll
        for (int c = 0; c < 8; ++c) {
            const int g = gi * 8 + c;
            if (g < 50) {
                const float4 h1r = *(const float4*)&sm[TOFF_H1T + g * 132 + mrow];
                const float bias = sm[TOFF_B2 + half * 50 + g];
                float* out = T + ((size_t)e * NK + k0 + mrow) * 100 + half * 50 + g;
                out[0]   = fast_tanh(acc[0][c] + bias) + h1r.x;
                out[100] = fast_tanh(acc[1][c] + bias) + h1r.y;
                out[200] = fast_tanh(acc[2][c] + bias) + h1r.z;
                out[300] = fast_tanh(acc[3][c] + bias) + h1r.w;
            }
        }
    }
}

// ---------------------------------------------------------------------------
// k_xyz: per atom: gather+lerp G from table, reduce xyz[c][g], emit DR (f16).
// (unchanged — proven)
// ---------------------------------------------------------------------------
__global__ __launch_bounds__(256) void k_xyz(
    const float* __restrict__ Ri, const float* __restrict__ T,
    _Float16* __restrict__ DRh)
{
    __shared__ float4 sR[256];
    __shared__ float  sF[256];
    __shared__ int    sI[256];
    __shared__ float  sXYZ[400];

    const int t   = threadIdx.x;
    const int blk = blockIdx.x;          // 0..2047
    const int b   = blk >> 9;
    const int i   = (blk >> 8) & 1;
    const int n   = blk & 255;

    for (int idx = t; idx < 400; idx += 256) sXYZ[idx] = 0.f;

    {
        const int jj = t >> 7, m = t & 127;
        const size_t row = ((size_t)(b * 512 + i * 256 + n)) * 256 + jj * 128 + m;
        const float4 r = *(const float4*)(Ri + row * 4);
        sR[t] = r;
        float u = (r.x - TLO) * TINVH;
        int ii = (int)u;
        ii = (ii < 0) ? 0 : ((ii > NK - 2) ? NK - 2 : ii);
        sI[t] = ii;
        sF[t] = u - (float)ii;
    }
    __syncthreads();

    const int jj = t >> 7;
    const int g  = t & 127;
    if (g < 100) {
        const float* Te = T + ((size_t)(i * 2 + jj)) * NK * 100 + g;
        float a0 = 0.f, a1 = 0.f, a2 = 0.f, a3 = 0.f;
        #pragma unroll 4
        for (int m = 0; m < 128; ++m) {
            const int s = jj * 128 + m;
            const float4 R = sR[s];
            const float  f = sF[s];
            const float* p = Te + (size_t)sI[s] * 100;
            const float v0 = p[0], v1 = p[100];
            const float G = v0 + f * (v1 - v0);
            a0 += R.x * G; a1 += R.y * G; a2 += R.z * G; a3 += R.w * G;
        }
        atomicAdd(&sXYZ[g],       a0);
        atomicAdd(&sXYZ[100 + g], a1);
        atomicAdd(&sXYZ[200 + g], a2);
        atomicAdd(&sXYZ[300 + g], a3);
    }
    __syncthreads();

    const float inv = 1.0f / 65536.0f;
    _Float16* dr = DRh + (((size_t)i * 4 + b) * 256 + n) * FIT_IN;
    for (int q = t; q < 400; q += 256) {
        const int gg = q >> 2, h0 = (q & 3) * 4;
        ushort4 pk;
        _Float16* ph = (_Float16*)&pk;
        #pragma unroll
        for (int r = 0; r < 4; ++r) {
            const int h = h0 + r;
            const float v = (sXYZ[gg] * sXYZ[h] + sXYZ[100 + gg] * sXYZ[100 + h]
                           + sXYZ[200 + gg] * sXYZ[200 + h] + sXYZ[300 + gg] * sXYZ[300 + h]) * inv;
            ph[r] = (_Float16)v;
        }
        *(ushort4*)(dr + gg * 16 + h0) = pk;
    }
}

// ---------------------------------------------------------------------------
// k_fit_mfma: layer-0 partial GEMM P[ks] = A[rows, kslice] @ W[kslice, 240].
// (unchanged from R10 — proven, ~16us)
// ---------------------------------------------------------------------------
template<int K, int CHUNK>
__global__ __launch_bounds__(256) void k_fit_mfma(
    const _Float16* __restrict__ A, const _Float16* __restrict__ WT,
    float* __restrict__ P)
{
    __shared__ _Float16 sA[64 * 40];     // [m][k] stride 40 (80 B, 16B-aligned)
    __shared__ _Float16 sBT[240 * 40];   // [n][k] stride 40

    const int t    = threadIdx.x;
    const int w    = t >> 6;
    const int lane = t & 63;
    const int ln   = lane & 15;
    const int quad = lane >> 4;

    const int mtile = blockIdx.x;        // 0..31
    const int ks    = blockIdx.y;
    const int row0  = mtile * 64;
    const int tp    = mtile >> 4;
    const int kbeg  = ks * CHUNK;
    const int kend  = (kbeg + CHUNK < K) ? (kbeg + CHUNK) : K;
    const int nf0   = w * 4;
    const int nfrags = (w < 3) ? 4 : 3;

    f4v acc[4][4];
    #pragma unroll
    for (int mf = 0; mf < 4; ++mf)
        #pragma unroll
        for (int nf = 0; nf < 4; ++nf) acc[mf][nf] = (f4v)0.f;

    const _Float16* Ab = A + (size_t)row0 * K;
    const _Float16* Wb = WT + (size_t)tp * 240 * K;

    for (int k0 = kbeg; k0 < kend; k0 += 32) {
        // stage A tile 64x32 (uint2 = 4 f16)
        #pragma unroll
        for (int q = t; q < 512; q += 256) {
            const int m = q >> 3, kq = (q & 7) * 4;
            const int k = k0 + kq;
            uint2 v = make_uint2(0u, 0u);
            if (k < kend) v = *(const uint2*)(Ab + (size_t)m * K + k);
            *(uint2*)&sA[m * 40 + kq] = v;
        }
        // stage W tile 240x32 from transposed WT (coalesced)
        for (int q = t; q < 1920; q += 256) {
            const int n = q >> 3, kq = (q & 7) * 4;
            const int k = k0 + kq;
            uint2 v = make_uint2(0u, 0u);
            if (k < kend) v = *(const uint2*)(Wb + (size_t)n * K + k);
            *(uint2*)&sBT[n * 40 + kq] = v;
        }
        __syncthreads();

        h8 afr[4];
        #pragma unroll
        for (int mf = 0; mf < 4; ++mf)
            afr[mf] = *(const h8*)&sA[(mf * 16 + ln) * 40 + quad * 8];
        #pragma unroll
        for (int nf = 0; nf < 4; ++nf) {
            if (nf < nfrags) {
                const h8 bfr = *(const h8*)&sBT[((nf0 + nf) * 16 + ln) * 40 + quad * 8];
                #pragma unroll
                for (int mf = 0; mf < 4; ++mf)
                    acc[mf][nf] = __builtin_amdgcn_mfma_f32_16x16x32_f16(
                        afr[mf], bfr, acc[mf][nf], 0, 0, 0);
            }
        }
        __syncthreads();
    }

    float* Pb = P + ((size_t)ks * 2048 + row0) * FH;
    #pragma unroll
    for (int nf = 0; nf < 4; ++nf) {
        if (nf < nfrags) {
            const int col = (nf0 + nf) * 16 + ln;
            #pragma unroll
            for (int mf = 0; mf < 4; ++mf)
                #pragma unroll
                for (int r = 0; r < 4; ++r) {
                    const int row = mf * 16 + quad * 4 + r;
                    Pb[(size_t)row * FH + col] = acc[mf][nf][r];
                }
        }
    }
}

// ---------------------------------------------------------------------------
// k_fit_tail: 128 blocks x 16 rows, 256 thr. (unchanged from R10 — proven,
// ~25us: 8-slice P reduce + batched-reg-staged W quarters + W3 dot)
// ---------------------------------------------------------------------------
__global__ __launch_bounds__(256) void k_fit_tail(
    const float* __restrict__ P,
    const _Float16* __restrict__ W1T, const _Float16* __restrict__ W2T,
    const float* __restrict__ fb0, const float* __restrict__ fb1,
    const float* __restrict__ fb2, const float* __restrict__ fW3,
    const float* __restrict__ fb3, float* __restrict__ out)
{
    __shared__ _Float16 sStage[64 * 248];     // 31.7 KB, W quarter [n_local][k]
    __shared__ _Float16 sAbuf[2][16 * 264];   // 2 x 8.4 KB, f16 A ping-pong
    __shared__ float    hRes[16 * 240];       // 15.4 KB, residual (single-owner)

    const int t    = threadIdx.x;
    const int w    = t >> 6;                  // 0..3
    const int lane = t & 63;
    const int ln   = lane & 15;
    const int quad = lane >> 4;
    const int r0   = blockIdx.x * 16;         // 0..2032
    const int tp   = r0 >> 10;

    // zero both sA buffers (covers k-pad cols 240..263)
    for (int q = t; q < 2 * 16 * 264; q += 256) ((_Float16*)sAbuf)[q] = (_Float16)0.f;
    // zero-fill sStage pad cols 240..247 for all 64 rows (NaN fix)
    if (t < 128) {
        const int n = t >> 1, kq = 240 + (t & 1) * 4;
        *(uint2*)&sStage[n * 248 + kq] = make_uint2(0u, 0u);
    }

    // ---- phase A: reduce P over 8 slices, +bias, tanh -> h0 ----
    #pragma unroll
    for (int j = 0; j < 15; ++j) {
        const int e = t + j * 256;            // 0..3839 == 16*240 exactly
        const int m = e / 240, col = e - m * 240;
        const size_t base = (size_t)(r0 + m) * FH + col;
        float s = 0.f;
        #pragma unroll
        for (int ks = 0; ks < KSPLIT0; ++ks)
            s += P[(size_t)ks * 2048 * FH + base];
        const float v = fast_tanh(s + fb0[tp * FH + col]);
        hRes[m * 240 + col] = v;
        sAbuf[0][m * 264 + col] = (_Float16)v;
    }

    // ---- layers 1,2: four 64-row quarters, batched reg staging ----
    for (int layer = 0; layer < 2; ++layer) {
        const _Float16* Wt = (layer == 0 ? W1T : W2T) + (size_t)tp * FH * FH;
        const float* Bias  = (layer == 0 ? fb1 : fb2) + tp * FH;
        const _Float16* inA = sAbuf[layer];
        _Float16* outA      = sAbuf[layer ^ 1];

        for (int p = 0; p < 4; ++p) {
            __syncthreads();                  // prev quarter's sStage reads done
            const int rmax = (p < 3) ? 63 : 47;   // clamp src row (last quarter)
            uint2 ld[15];
            #pragma unroll
            for (int j = 0; j < 15; ++j) {    // 15 independent loads, no guard
                const int q = t + j * 256;    // 0..3839; 60 uint2 per row
                const int n = q / 60, kq = (q - n * 60) * 4;
                const int nc = (n > rmax) ? rmax : n;
                ld[j] = *(const uint2*)(Wt + (size_t)(p * 64 + nc) * FH + kq);
            }
            #pragma unroll
            for (int j = 0; j < 15; ++j) {    // write-late (one waitcnt above)
                const int q = t + j * 256;
                const int n = q / 60, kq = (q - n * 60) * 4;
                *(uint2*)&sStage[n * 248 + kq] = ld[j];
            }
            __syncthreads();                  // stage visible

            const int f = p * 4 + w;          // frag this wave owns this quarter
            if (f < 15) {
                f4v acc = (f4v)0.f;
                #pragma unroll
                for (int s = 0; s < 8; ++s) { // K=240 padded to 256; pads are 0
                    const h8 afr = *(const h8*)&inA[ln * 264 + s * 32 + quad * 8];
                    const h8 bfr = *(const h8*)&sStage[(w * 16 + ln) * 248 + s * 32 + quad * 8];
                    acc = __builtin_amdgcn_mfma_f32_16x16x32_f16(afr, bfr, acc, 0, 0, 0);
                }
                const int col = f * 16 + ln;
                const float bias = Bias[col];
                #pragma unroll
                for (int r = 0; r < 4; ++r) {
                    const int m = quad * 4 + r;
                    const float v = fast_tanh(acc[r] + bias) + hRes[m * 240 + col];
                    hRes[m * 240 + col] = v;          // single-owner slot
                    outA[m * 264 + col] = (_Float16)v;
                }
            }
        }
    }
    __syncthreads();                          // h2 (hRes) complete

    // ---- out: per-wave row dot with W3 (h2 in hRes) ----
    const float* wv = fW3 + tp * FH;
    #pragma unroll
    for (int rr = 0; rr < 4; ++rr) {
        const int m = w * 4 + rr;
        float s = 0.f;
        for (int k = lane; k < FH; k += 64)
            s += hRes[m * 240 + k] * wv[k];
        #pragma unroll
        for (int off = 32; off > 0; off >>= 1) s += __shfl_down(s, off);
        if (lane == 0) {
            const int gr = r0 + m;
            const int b = (gr >> 8) & 3, n = gr & 255;
            out[b * 512 + tp * 256 + n] = s + fb3[tp];
        }
    }
}

// ---------------------------------------------------------------------------
extern "C" void kernel_launch(void* const* d_in, const int* in_sizes, int n_in,
                              void* d_out, int out_size, void* d_ws, size_t ws_size,
                              hipStream_t stream)
{
    const float* Ri  = (const float*)d_in[0];
    const float* eW0 = (const float*)d_in[1];
    const float* eB0 = (const float*)d_in[2];
    const float* eW1 = (const float*)d_in[3];
    const float* eB1 = (const float*)d_in[4];
    const float* eW2 = (const float*)d_in[5];
    const float* eB2 = (const float*)d_in[6];
    const float* fW0 = (const float*)d_in[7];
    const float* fb0 = (const float*)d_in[8];
    const float* fW1 = (const float*)d_in[9];
    const float* fb1 = (const float*)d_in[10];
    const float* fW2 = (const float*)d_in[11];
    const float* fb2 = (const float*)d_in[12];
    const float* fW3 = (const float*)d_in[13];
    const float* fb3 = (const float*)d_in[14];

    // workspace layout (bytes)
    char* p = (char*)d_ws;
    float* T   = (float*)p;                 p += (size_t)4 * NK * 100 * 4;           // 3.28 MB
    float* P   = (float*)p;                 p += (size_t)KSPLIT0 * 2048 * FH * 4;    // 15.7 MB
    _Float16* DRh = (_Float16*)p;           p += (size_t)2048 * FIT_IN * 2;          // 6.55 MB
    _Float16* W0T = (_Float16*)p;           p += (size_t)768000 * 2;                 // 1.54 MB
    _Float16* W1T = (_Float16*)p;           p += (size_t)115200 * 2;
    _Float16* W2T = (_Float16*)p;           p += (size_t)115200 * 2;

    k_prep<<<dim3(512), dim3(256), 0, stream>>>(eW0, eB0, eW1, eB1, eW2, eB2, T,
                                                fW0, fW1, fW2, W0T, W1T, W2T);
    k_xyz<<<dim3(2048), dim3(256), 0, stream>>>(Ri, T, DRh);

    // layer 0 partial GEMM: K=1600, CHUNK=200, KSPLIT=8, 64-row tiles
    k_fit_mfma<FIT_IN, CHUNK0><<<dim3(32, KSPLIT0), dim3(256), 0, stream>>>(DRh, W0T, P);

    // fused tail: 8-slice reduce + layer1 + layer2 + output dot (batched staging)
    k_fit_tail<<<dim3(128), dim3(256), 0, stream>>>(P, W1T, W2T, fb0, fb1, fb2, fW3, fb3,
                                                    (float*)d_out);
}